// Round 11
// baseline (839.534 us; speedup 1.0000x reference)
//
#include <hip/hip_runtime.h>
#include <cstdint>

#define BB 8
#define CC 128
#define HH 96
#define WW 160
#define HWsz (HH * WW)                 // 15360
#define TH 8
#define TW 32
#define CSTEP 8
#define HALO_H 16                      // TH + 8
#define SW2 64                         // x2 row stride in words, POWER OF 2 (R9 bank algebra)
#define CI_WORDS (HALO_H * SW2)        // 1024 words = 4 KB per channel slice
#define X2W (CSTEP * CI_WORDS)         // 8192 words = 32 KB per x2 buffer
#define X1W (CSTEP * TH * TW)          // 2048 words = 8 KB per x1 buffer
#define X2_SLOTS (X2W / 64)            // 128 row-slots per chunk
#define X1_SLOTS (X1W / 64)            // 32
#define NSTG2 15                       // x2 stage loads per wave (uniform, redirect scheme)
#define NWAVES 9
#define NTHREADS (NWAVES * 64)         // 576
#define NCHUNKS (CC / CSTEP)           // 16
#define NBLOCKS (BB * (HH / TH) * (WW / TW))  // 480
#define X2B (3 * X1W)                  // x2 region base (x1 first: small static offsets)
// LDS: 3 x1 bufs (24 KB) + 3 x2 bufs (96 KB) = 30720 words = 120 KB (1 block/CU,
// which rocprof shows has been the reality all session anyway).

__device__ __forceinline__ void g2l_dword(const float* g, float* l) {
  __builtin_amdgcn_global_load_lds((const __attribute__((address_space(1))) void*)g,
                                   (__attribute__((address_space(3))) void*)l,
                                   4, 0, 0);
}

// R11: single-barrier 3-deep pipeline, compile-time buffer rotation.
// Per chunk k: [vmcnt(19)][s_barrier][compute k (pure LDS)][issue stage(k+2)].
// RAW: stage(k) issued 2 iters ago; vmcnt(19) keeps only stage(k+1) (19 newest),
//      drains stage(k); barrier makes it all-waves.
// WAR: stage(k+2) writes buf (k+2)%3; its last reader was compute(k-1), which
//      every wave finished BEFORE arriving at barrier(k); issuing wave passed
//      barrier(k). Max inter-wave drift = 1 barrier -> 3 buffers suffice.
// No runtime rotation state (R8's spill source): the main loop is unrolled x3
// with static buffer indices; global src pointers roll by += CSTEP*HWsz (SGPR).
// Compute is pure LDS -> no compiler vmem wait can force-drain the stage queue
// (R10's regression mechanism: vmcnt is a FIFO — waiting on a newer load
// drains ALL older; x1 therefore lives in LDS, 3-deep like x2).
extern "C" __global__ void __launch_bounds__(NTHREADS, 1)
corr81_kernel(const float* __restrict__ x1, const float* __restrict__ x2,
              float* __restrict__ out)
{
  __shared__ __align__(16) float lds[3 * X1W + 3 * X2W];   // 120 KB

  const int tid  = threadIdx.x;
  const int wv   = tid >> 6;                              // dy 0..8 (wave-uniform)
  const int wvu  = __builtin_amdgcn_readfirstlane(wv);
  const int lane = tid & 63;
  const int r    = lane >> 3;    // tile row 0..7
  const int j    = lane & 7;     // w-slot 0..7 (4 px each)

  // XCD-bijective swizzle (validated: FETCH 184 -> 65 MB).
  const int bid0 = blockIdx.x;
  const int bid  = (bid0 & 7) * (NBLOCKS / 8) + (bid0 >> 3);

  const int wt = bid % (WW / TW);
  const int ht = (bid / (WW / TW)) % (HH / TH);
  const int b  = bid / ((WW / TW) * (HH / TH));
  const int h0 = ht * TH;
  const int w0 = wt * TW;

  // ---- per-lane staged-column VGPRs (R9-proven): slot i uses group i&3,
  // m = (wvu+i)&3 since 9i ≡ i mod 4. Clamp folds replicate-pad.
  int gw[4];
#pragma unroll
  for (int g = 0; g < 4; ++g) {
    const int m  = (wvu + g) & 3;
    const int cl = lane ^ (m << 2);              // logical col this lane stages
    int gwv = w0 + cl - 4;
    gwv = gwv < 0 ? 0 : (gwv > WW - 1 ? WW - 1 : gwv);
    gw[g] = gwv;
  }
  // slot 14 redirect: idx >= 128 -> own slot 0 (same src+dst bytes, benign WAW).
  const int gw14v = (wvu + 9 * 14 < X2_SLOTS) ? gw[14 & 3] : gw[0];

  // ---- wave-uniform scalar staging addresses (SGPRs), R9-proven.
  int sb2[NSTG2]; uint32_t doff2[NSTG2];
#pragma unroll
  for (int i = 0; i < NSTG2; ++i) {
    int idx = wvu + 9 * i;
    if (idx >= X2_SLOTS) idx = wvu;              // redirect to own slot 0
    const int ci  = idx >> 4;
    const int row = idx & 15;
    int gh = h0 + row - 4; gh = gh < 0 ? 0 : (gh > HH - 1 ? HH - 1 : gh);
    sb2[i]  = (ci * HH + gh) * WW;
    doff2[i] = (uint32_t)(idx * 64);
  }
  // x1 staging (R9-proven): 32 slots, 4/wave, clamp-dup benign (linear layout).
  const int voff1 = (lane & 31) + (lane >> 5) * WW;   // per-lane part (1 VGPR)
  int sb1[4]; uint32_t doff1[4];
#pragma unroll
  for (int i = 0; i < 4; ++i) {
    int idx = wvu + 9 * i; if (idx >= X1_SLOTS) idx = X1_SLOTS - 1;
    const int ci = idx >> 2;
    sb1[i]  = ci * HWsz + (h0 + (idx & 3) * 2) * WW + w0;
    doff1[i] = (uint32_t)(idx * 64);
  }

  const float* x2b = x2 + (size_t)b * CC * HWsz;
  const float* x1b = x1 + (size_t)b * CC * HWsz;

  float acc[9][4];
#pragma unroll
  for (int d = 0; d < 9; ++d)
#pragma unroll
    for (int p = 0; p < 4; ++p) acc[d][p] = 0.f;

  // x2 read bases (R9-proven): phys word = R*64 + 4*((j+t)^m), m = R&3.
  const int R = r + wv;
  const int m = R & 3;
  const int B0 = R * SW2 + (((j + 0) ^ m) << 2);
  const int B1 = R * SW2 + (((j + 1) ^ m) << 2);
  const int B2 = R * SW2 + (((j + 2) ^ m) << 2);
  const int abase = r * TW + 4 * j;              // x1 LDS read base (words)

#define STAGE(SB, SP2, SP1)                                                  \
  {                                                                          \
    float* d2 = &lds[X2B + (SB) * X2W];                                      \
    float* d1 = &lds[(SB) * X1W];                                            \
    _Pragma("unroll")                                                        \
    for (int i = 0; i < NSTG2 - 1; ++i)                                      \
      g2l_dword((SP2) + sb2[i] + gw[i & 3], d2 + doff2[i]);                  \
    g2l_dword((SP2) + sb2[14] + gw14v, d2 + doff2[14]);                      \
    _Pragma("unroll")                                                        \
    for (int i = 0; i < 4; ++i)                                              \
      g2l_dword((SP1) + sb1[i] + voff1, d1 + doff1[i]);                      \
  }

#define COMPUTE(CB)                                                          \
  {                                                                          \
    const float* xb = &lds[X2B + (CB) * X2W];                                \
    const float* ab = &lds[(CB) * X1W] + abase;                              \
    _Pragma("unroll")                                                        \
    for (int ci = 0; ci < CSTEP; ++ci) {                                     \
      const float4 a4 = *(const float4*)(ab + ci * (TH * TW));               \
      const float4 f0 = *(const float4*)(xb + B0 + ci * CI_WORDS);           \
      const float4 f1 = *(const float4*)(xb + B1 + ci * CI_WORDS);           \
      const float4 f2 = *(const float4*)(xb + B2 + ci * CI_WORDS);           \
      const float av[4] = {a4.x, a4.y, a4.z, a4.w};                          \
      const float w12[12] = {f0.x, f0.y, f0.z, f0.w, f1.x, f1.y, f1.z,       \
                             f1.w, f2.x, f2.y, f2.z, f2.w};                  \
      _Pragma("unroll")                                                      \
      for (int d = 0; d < 9; ++d)                                            \
        _Pragma("unroll")                                                    \
        for (int p = 0; p < 4; ++p)                                          \
          acc[d][p] = fmaf(av[p], w12[d + p], acc[d][p]);                    \
    }                                                                        \
  }

#define BODY(CB, SB)                                                         \
  {                                                                          \
    __builtin_amdgcn_sched_barrier(0);                                       \
    asm volatile("s_waitcnt vmcnt(19)" ::: "memory");                        \
    __builtin_amdgcn_sched_barrier(0);                                       \
    __builtin_amdgcn_s_barrier();                                            \
    __builtin_amdgcn_sched_barrier(0);                                       \
    COMPUTE(CB)                                                              \
    if (kst < NCHUNKS) {                                                     \
      STAGE(SB, sp2, sp1)                                                    \
      sp2 += CSTEP * HWsz;                                                   \
      sp1 += CSTEP * HWsz;                                                   \
      ++kst;                                                                 \
    }                                                                        \
  }

  // ---- prologue: stage chunks 0 and 1 into bufs 0 and 1 (19 + 19 loads)
  STAGE(0, x2b, x1b)
  STAGE(1, x2b + (size_t)(CSTEP * HWsz), x1b + (size_t)(CSTEP * HWsz))

  int kst = 2;                                   // next chunk to stage
  const float* sp2 = x2b + (size_t)2 * (CSTEP * HWsz);
  const float* sp1 = x1b + (size_t)2 * (CSTEP * HWsz);

  // ---- main loop: chunks 0..14, unrolled x3 for static buffer rotation
#pragma unroll 1
  for (int t = 0; t < 5; ++t) {
    BODY(0, 2)   // k = 3t   : compute buf 0, stage into buf 2
    BODY(1, 0)   // k = 3t+1 : compute buf 1, stage into buf 0
    BODY(2, 1)   // k = 3t+2 : compute buf 2, stage into buf 1
  }

  // ---- peeled chunk 15 (buf 15%3 = 0): nothing left in flight to preserve
  __builtin_amdgcn_sched_barrier(0);
  asm volatile("s_waitcnt vmcnt(0)" ::: "memory");
  __builtin_amdgcn_sched_barrier(0);
  __builtin_amdgcn_s_barrier();
  __builtin_amdgcn_sched_barrier(0);
  COMPUTE(0)

  // ---- epilogue (R0/R3 verbatim): out[((b*81 + wv*9+d)*H + h0+r)*W + w0+4j], /8
  float* op = out + (((size_t)b * 81 + (size_t)wv * 9) * HH + (h0 + r)) * WW + (w0 + 4 * j);
#pragma unroll
  for (int d = 0; d < 9; ++d) {
    float4 v;
    v.x = acc[d][0] * 0.125f;
    v.y = acc[d][1] * 0.125f;
    v.z = acc[d][2] * 0.125f;
    v.w = acc[d][3] * 0.125f;
    *(float4*)(op + (size_t)d * HWsz) = v;
  }
}

extern "C" void kernel_launch(void* const* d_in, const int* in_sizes, int n_in,
                              void* d_out, int out_size, void* d_ws, size_t ws_size,
                              hipStream_t stream) {
  const float* x1 = (const float*)d_in[0];
  const float* x2 = (const float*)d_in[1];
  float* out = (float*)d_out;
  corr81_kernel<<<dim3(NBLOCKS), dim3(NTHREADS), 0, stream>>>(x1, x2, out);
}

// Round 12
// 276.187 us; speedup vs baseline: 3.0397x; 3.0397x over previous
//
#include <hip/hip_runtime.h>
#include <cstdint>

#define BB 8
#define CC 128
#define HH 96
#define WW 160
#define HWsz (HH * WW)                 // 15360
#define TH 8
#define TW 32
#define CSTEP 4
#define NCH (CC / CSTEP)               // 32 chunks
#define SW2 64                         // LDS row stride, power of 2 (R9 bank algebra)
#define CI_WORDS (TH * SW2)            // 512 words = 2 KB per channel slice (8 rows)
#define X2W (CSTEP * CI_WORDS)         // 2048 words = 8 KB per buffer
#define NTILES (BB * (HH / TH) * (WW / TW))   // 480
#define NBLOCKS (NTILES * 9)           // 4320 one-wave blocks (tile x dy)

__device__ __forceinline__ void g2l_dword(const float* g, float* l) {
  __builtin_amdgcn_global_load_lds((const __attribute__((address_space(1))) void*)g,
                                   (__attribute__((address_space(3))) void*)l,
                                   4, 0, 0);
}

// R12: ZERO-BARRIER per-wave pipeline. Session finding: all valid kernels sit
// at 108-124 us with Occupancy ~23% => ONE 9-wave block/CU, lockstep, 2 barrier
// rendezvous per chunk = the invariant cost no counter-level fix touched.
// Here each block is ONE wave owning one (tile, dy): it stages its own 8 halo
// rows (swizzled, R9-proven layout with R->r) into a private 2-deep LDS buffer
// and syncs only via counted vmcnt. ~10 blocks/CU overlap each other's stalls.
//
// FIFO discipline (R10's lesson: vmcnt is a FIFO; a wait for a NEWER load
// drains ALL older): per iter k the issue order is
//   [top]    stage(k+1): 32 g2l            (newest)
//   [wait]   vmcnt(32) -> drains pf(k) + stage(k), keeps stage(k+1) in flight
//   [compute k] pure LDS + regs
//   [bottom] pf(k+1): 4 global float4      (now newest)
// So the wait for pf(k) (issued last iter's bottom) is the SAME vmcnt(32) —
// the stage queue is never force-drained. Outstanding peaks at 68 > 63: the HW
// counter saturates and stalls ISSUE briefly; harmless for correctness.
// LDS WAR: single wave owns both buffers; program order suffices. No s_barrier.
// Registers: acc 36 + pf 16 + gw 4 + B 3 + misc ~ 83 <= 84 budget (WRITE_SIZE
// 38880 is the spill tripwire).
extern "C" __global__ void __launch_bounds__(64, 1)
corr81_kernel(const float* __restrict__ x1, const float* __restrict__ x2,
              float* __restrict__ out)
{
  __shared__ __align__(16) float lds[2 * X2W];   // 16 KB -> ~10 blocks/CU

  const int lane = threadIdx.x;      // 0..63
  const int r    = lane >> 3;        // tile row 0..7
  const int j    = lane & 7;         // w-slot 0..7 (4 px each)

  // XCD-bijective swizzle over 4320 (4320 % 8 == 0; 540 consecutive logical
  // blocks = 60 tiles x 9 dy per XCD -> halo re-reads L2-local, validated).
  const int bid0 = blockIdx.x;
  const int bid  = (bid0 & 7) * (NBLOCKS / 8) + (bid0 >> 3);
  const int tile = bid / 9;
  const int wv   = bid - 9 * tile;   // dy index 0..8
  const int wt   = tile % (WW / TW);
  const int ht   = (tile / (WW / TW)) % (HH / TH);
  const int b    = tile / ((WW / TW) * (HH / TH));
  const int h0   = ht * TH;
  const int w0   = wt * TW;

  // ---- per-lane staged columns, one per row-swizzle class m = row&3.
  // Phys word l of a row holds logical col l ^ (m<<2); only lanes<48 stage
  // (cols 0..47 cover all read blocks: ((j+t)^m) <= 11). Clamp = replicate pad.
  int gw[4];
#pragma unroll
  for (int g = 0; g < 4; ++g) {
    const int cl = lane ^ (g << 2);
    int gwv = w0 + cl - 4;
    gwv = gwv < 0 ? 0 : (gwv > WW - 1 ? WW - 1 : gwv);
    gw[g] = gwv;
  }

  // ---- uniform row bases (SGPR-resident), dy folded into the staged rows:
  // slot i = (ci = i>>3, row = i&7) -> global row h0 + wv + row - 4 clamped.
  int sb2[32];
#pragma unroll
  for (int i = 0; i < 32; ++i) {
    const int ci  = i >> 3;
    const int row = i & 7;
    int gh = h0 + wv + row - 4; gh = gh < 0 ? 0 : (gh > HH - 1 ? HH - 1 : gh);
    sb2[i] = (ci * HH + gh) * WW;
  }

  const float* x2b = x2 + (size_t)b * CC * HWsz;
  const float* x1c = x1 + (size_t)b * CC * HWsz + (size_t)(h0 + r) * WW + (w0 + 4 * j);

  float acc[9][4];
#pragma unroll
  for (int d = 0; d < 9; ++d)
#pragma unroll
    for (int p = 0; p < 4; ++p) acc[d][p] = 0.f;

  // x2 LDS read bases (R9-proven involution, R -> local row r): m = r&3.
  const int m  = r & 3;
  const int B0 = r * SW2 + (((j + 0) ^ m) << 2);
  const int B1 = r * SW2 + (((j + 1) ^ m) << 2);
  const int B2 = r * SW2 + (((j + 2) ^ m) << 2);

#define STAGE(DST, SRC)                                                      \
  if (lane < 48) {                                                           \
    _Pragma("unroll")                                                        \
    for (int i = 0; i < 32; ++i)                                             \
      g2l_dword((SRC) + sb2[i] + gw[i & 3], (DST) + i * 64);                 \
  }

#define COMPUTE(XB)                                                          \
  {                                                                          \
    _Pragma("unroll")                                                        \
    for (int ci = 0; ci < CSTEP; ++ci) {                                     \
      const float av[4] = {pf[ci].x, pf[ci].y, pf[ci].z, pf[ci].w};          \
      const float4 f0 = *(const float4*)((XB) + B0 + ci * CI_WORDS);         \
      const float4 f1 = *(const float4*)((XB) + B1 + ci * CI_WORDS);         \
      const float4 f2 = *(const float4*)((XB) + B2 + ci * CI_WORDS);         \
      const float w12[12] = {f0.x, f0.y, f0.z, f0.w, f1.x, f1.y, f1.z,       \
                             f1.w, f2.x, f2.y, f2.z, f2.w};                  \
      _Pragma("unroll")                                                      \
      for (int d = 0; d < 9; ++d)                                            \
        _Pragma("unroll")                                                    \
        for (int p = 0; p < 4; ++p)                                          \
          acc[d][p] = fmaf(av[p], w12[d + p], acc[d][p]);                    \
    }                                                                        \
  }

  float4 pf[4];   // x1 prefetch, all indices compile-time (rule #20)

  // ---- prologue: stage(0) then pf(0)  (FIFO: [stage0 32][pf0 4])
  STAGE(&lds[0], x2b)
#pragma unroll
  for (int q = 0; q < CSTEP; ++q)
    pf[q] = *(const float4*)(x1c + (size_t)q * HWsz);

#pragma unroll 1
  for (int k = 0; k < NCH - 1; ++k) {
    // [top] issue stage(k+1) — precomputed offsets, SGPR base rolls
    __builtin_amdgcn_sched_barrier(0);
    {
      const float* s2 = x2b + (size_t)(k + 1) * (CSTEP * HWsz);
      float* d2 = &lds[((k + 1) & 1) * X2W];
      STAGE(d2, s2)
    }
    // [wait] drains pf(k)+stage(k); keeps stage(k+1)'s 32 in flight
    __builtin_amdgcn_sched_barrier(0);
    asm volatile("s_waitcnt vmcnt(32)" ::: "memory");
    __builtin_amdgcn_sched_barrier(0);

    // [compute k] pure LDS + regs (no vmem -> nothing can drain the queue)
    COMPUTE(&lds[(k & 1) * X2W])

    // [bottom] issue pf(k+1) — newest in FIFO; reg deps keep it after pf reads
    {
      const float* xn = x1c + (size_t)(k + 1) * (CSTEP * HWsz);
#pragma unroll
      for (int q = 0; q < CSTEP; ++q)
        pf[q] = *(const float4*)(xn + (size_t)q * HWsz);
    }
  }

  // ---- peeled last chunk (k = 31, buf 1): drain everything
  __builtin_amdgcn_sched_barrier(0);
  asm volatile("s_waitcnt vmcnt(0)" ::: "memory");
  __builtin_amdgcn_sched_barrier(0);
  COMPUTE(&lds[((NCH - 1) & 1) * X2W])

  // ---- epilogue (R3 verbatim): out[((b*81 + wv*9+d)*H + h0+r)*W + w0+4j], /8
  float* op = out + (((size_t)b * 81 + (size_t)wv * 9) * HH + (h0 + r)) * WW + (w0 + 4 * j);
#pragma unroll
  for (int d = 0; d < 9; ++d) {
    float4 v;
    v.x = acc[d][0] * 0.125f;
    v.y = acc[d][1] * 0.125f;
    v.z = acc[d][2] * 0.125f;
    v.w = acc[d][3] * 0.125f;
    *(float4*)(op + (size_t)d * HWsz) = v;
  }
}

extern "C" void kernel_launch(void* const* d_in, const int* in_sizes, int n_in,
                              void* d_out, int out_size, void* d_ws, size_t ws_size,
                              hipStream_t stream) {
  const float* x1 = (const float*)d_in[0];
  const float* x2 = (const float*)d_in[1];
  float* out = (float*)d_out;
  corr81_kernel<<<dim3(NBLOCKS), dim3(64), 0, stream>>>(x1, x2, out);
}

// Round 13
// 210.881 us; speedup vs baseline: 3.9811x; 1.3097x over previous
//
#include <hip/hip_runtime.h>
#include <cstdint>

#define BB 8
#define CC 128
#define HH 96
#define WW 160
#define HWsz (HH * WW)                 // 15360
#define TH 8
#define TW 32
#define CSTEP 8
#define HROWS 10                       // halo rows for a dy-triple: TH + 2
#define SW 48                          // x2 row stride (40 used + pad), swizzle-closed
#define CIW (HROWS * SW)               // 480 words per channel slice
#define X2W (CSTEP * CIW)              // 3840 words = 15 KB per x2 buffer
#define X1W (CSTEP * TH * TW)          // 2048 words = 8 KB per x1 buffer
#define NWAVES 3
#define NTHREADS (NWAVES * 64)         // 192
#define NCHUNKS (CC / CSTEP)           // 16
#define NTILES (BB * (HH / TH) * (WW / TW))   // 480
#define NBLOCKS (NTILES * 3)           // 1440 blocks = (tile, dy-triple)
#define X1B (2 * X2W)                  // x1 region base: 7680 words
// LDS: 2*X2W + 2*X1W = 11776 words = 47104 B -> 3 blocks/CU (141 KB <= 160)

__device__ __forceinline__ void g2l_dword(const float* g, float* l) {
  __builtin_amdgcn_global_load_lds((const __attribute__((address_space(1))) void*)g,
                                   (__attribute__((address_space(3))) void*)l,
                                   4, 0, 0);
}

// R13: 3-wave blocks (tile x dy-triple), grid 1440. Session synthesis: 9-wave
// blocks never co-schedule (occupancy ~23% = 1 block) so their 2 lockstep
// rendezvous/chunk leave DS-pipe bubbles nothing fills; 1-wave blocks (R12)
// have no internal TLP and stall on raw latency. 3-wave blocks give 3
// INDEPENDENT barrier domains per CU: one block's compute covers another's
// stage/barrier. Schedule per chunk = R3's proven 2-barrier counted-vmcnt.
// Staging is BY CHANNEL (wave wl owns ci 3wl..3wl+2, all 10 rows) so the
// swizzle class of every staged slot is row = i%10 -> COMPILE-TIME gw[row&3]
// (rule #20 safe); 8-channel remainder: wl=2's third channel redirects to its
// own ci=6 (identical src+dst bytes, benign WAW) keeping 42 loads/wave uniform.
// Swizzle (R2/R9-proven involution): phys 4-word block bl of row holds logical
// block bl^(row&3); closed on [0,12) since bl<=11, m<=3. Read granule algebra:
// (4R + (j+t)^m) mod 8 is bijective over j per (R,t) -> 2 lanes/granule per
// 16-lane phase = free 2-way floor.
extern "C" __global__ void __launch_bounds__(NTHREADS, 2)
corr81_kernel(const float* __restrict__ x1, const float* __restrict__ x2,
              float* __restrict__ out)
{
  __shared__ __align__(16) float lds[2 * X2W + 2 * X1W];   // 47104 B

  const int tid  = threadIdx.x;
  const int wvu  = __builtin_amdgcn_readfirstlane(tid >> 6);  // wave 0..2
  const int lane = tid & 63;
  const int r    = lane >> 3;    // tile row 0..7
  const int j    = lane & 7;     // w-slot 0..7 (4 px each)

  // XCD-bijective swizzle (validated): 1440 % 8 == 0; 180 consecutive logical
  // blocks (= 60 tiles x 3 dy-groups) per XCD -> halo re-reads L2-local.
  const int bid0 = blockIdx.x;
  const int bid  = (bid0 & 7) * (NBLOCKS / 8) + (bid0 >> 3);
  const int tile = bid / 3;
  const int g    = bid - 3 * tile;          // dy-triple index 0..2
  const int wt   = tile % (WW / TW);
  const int ht   = (tile / (WW / TW)) % (HH / TH);
  const int b    = tile / ((WW / TW) * (HH / TH));
  const int h0   = ht * TH;
  const int w0   = wt * TW;
  const int hb   = h0 + 3 * g - 4;          // halo row 0 source row (pre-clamp)

  // ---- scalar staging tables (all compile-time-indexed; ~26 SGPR values).
  int grw[HROWS];                           // clamped source row * WW
#pragma unroll
  for (int rr = 0; rr < HROWS; ++rr) {
    int v = hb + rr; v = v < 0 ? 0 : (v > HH - 1 ? HH - 1 : v);
    grw[rr] = v * WW;
  }
  int sc2[3], dc2[3], sx1[3], dx1[3];       // per-channel-group bases
#pragma unroll
  for (int c = 0; c < 3; ++c) {
    int ci = 3 * wvu + c; if (ci >= CSTEP) ci = 6;   // wl=2 remainder redirect
    sc2[c] = ci * HWsz;           // x2 source channel base
    dc2[c] = ci * CIW;            // x2 LDS channel base
    sx1[c] = ci * HWsz;           // x1 source channel base
    dx1[c] = ci * (TH * TW);      // x1 LDS channel base
  }
  int hqw[4];                               // x1 source row-pair bases
#pragma unroll
  for (int q = 0; q < 4; ++q) hqw[q] = (h0 + 2 * q) * WW + w0;

  // ---- per-lane staged columns, one per swizzle class m (4 VGPRs).
  int gw[4];
#pragma unroll
  for (int mm = 0; mm < 4; ++mm) {
    const int cl = lane ^ (mm << 2);        // logical col this phys word holds
    int v = w0 + cl - 4;
    gw[mm] = v < 0 ? 0 : (v > WW - 1 ? WW - 1 : v);
  }
  const int voff1 = (lane >> 5) * WW + (lane & 31);  // x1 per-lane part

  const float* x2b = x2 + (size_t)b * CC * HWsz;
  const float* x1b = x1 + (size_t)b * CC * HWsz;

  float acc[9][4];
#pragma unroll
  for (int d = 0; d < 9; ++d)
#pragma unroll
    for (int p = 0; p < 4; ++p) acc[d][p] = 0.f;

  // x2 LDS read bases: wave wl computes dy = 3g+wl -> halo row R = r + wl.
  const int R  = r + wvu;                   // 0..9
  const int m  = R & 3;
  const int B0 = R * SW + (((j + 0) ^ m) << 2);
  const int B1 = R * SW + (((j + 1) ^ m) << 2);
  const int B2 = R * SW + (((j + 2) ^ m) << 2);
  const int abase = r * TW + 4 * j;         // x1 LDS read base

  // 42 loads per wave per chunk (30 x2 + 12 x1), all counted uniformly.
#define STAGE(BUF, S2, S1)                                                   \
  {                                                                          \
    float* d2 = &lds[(BUF) * X2W];                                           \
    float* d1 = &lds[X1B + (BUF) * X1W];                                     \
    if (lane < SW) {                                                         \
      _Pragma("unroll")                                                      \
      for (int i = 0; i < 30; ++i) {                                         \
        const int c = i / 10, row = i % 10;                                  \
        g2l_dword((S2) + sc2[c] + grw[row] + gw[row & 3],                    \
                  d2 + dc2[c] + row * SW);                                   \
      }                                                                      \
    }                                                                        \
    _Pragma("unroll")                                                        \
    for (int i = 0; i < 12; ++i) {                                           \
      const int c = i / 4, q = i % 4;                                        \
      g2l_dword((S1) + sx1[c] + hqw[q] + voff1, d1 + dx1[c] + q * 64);       \
    }                                                                        \
  }

#define COMPUTE(BUF)                                                         \
  {                                                                          \
    const float* xb = &lds[(BUF) * X2W];                                     \
    const float* ab = &lds[X1B + (BUF) * X1W] + abase;                       \
    _Pragma("unroll")                                                        \
    for (int ci = 0; ci < CSTEP; ++ci) {                                     \
      const float4 a4 = *(const float4*)(ab + ci * (TH * TW));               \
      const float4 f0 = *(const float4*)(xb + B0 + ci * CIW);                \
      const float4 f1 = *(const float4*)(xb + B1 + ci * CIW);                \
      const float4 f2 = *(const float4*)(xb + B2 + ci * CIW);                \
      const float av[4] = {a4.x, a4.y, a4.z, a4.w};                          \
      const float w12[12] = {f0.x, f0.y, f0.z, f0.w, f1.x, f1.y, f1.z,       \
                             f1.w, f2.x, f2.y, f2.z, f2.w};                  \
      _Pragma("unroll")                                                      \
      for (int d = 0; d < 9; ++d)                                            \
        _Pragma("unroll")                                                    \
        for (int p = 0; p < 4; ++p)                                          \
          acc[d][p] = fmaf(av[p], w12[d + p], acc[d][p]);                    \
    }                                                                        \
  }

  // ---- prologue: stage chunk 0 into buffer 0
  STAGE(0, x2b, x1b)

#pragma unroll 1
  for (int k = 0; k < NCHUNKS - 1; ++k) {
    // [A] issue stage(k+1) — precomputed scalar bases + 5 per-lane VGPRs
    {
      const float* s2 = x2b + (size_t)(k + 1) * (CSTEP * HWsz);
      const float* s1 = x1b + (size_t)(k + 1) * (CSTEP * HWsz);
      STAGE((k + 1) & 1, s2, s1)
    }

    // [B] counted wait: drains stage(k)'s 42, keeps stage(k+1)'s 42 in flight
    __builtin_amdgcn_sched_barrier(0);
    asm volatile("s_waitcnt vmcnt(42)" ::: "memory");
    __builtin_amdgcn_sched_barrier(0);
    __builtin_amdgcn_s_barrier();             // 3-wave rendezvous (cheap)
    __builtin_amdgcn_sched_barrier(0);

    // [D] compute chunk k: 24 x2 + 8 x1 ds_read_b128, 288 FMA per lane
    COMPUTE(k & 1)

    // [C2] WAR barrier
    __builtin_amdgcn_sched_barrier(0);
    __builtin_amdgcn_s_barrier();
    __builtin_amdgcn_sched_barrier(0);
  }

  // ---- peeled last chunk (k = 15, buf 1): nothing left to prefetch
  asm volatile("s_waitcnt vmcnt(0)" ::: "memory");
  __builtin_amdgcn_sched_barrier(0);
  __builtin_amdgcn_s_barrier();
  __builtin_amdgcn_sched_barrier(0);
  COMPUTE((NCHUNKS - 1) & 1)

  // ---- epilogue: dy = 3g + wl; out[((b*81 + dy*9 + d)*H + h0+r)*W + w0+4j], /8
  const int dy = 3 * g + wvu;
  float* op = out + (((size_t)b * 81 + (size_t)dy * 9) * HH + (h0 + r)) * WW + (w0 + 4 * j);
#pragma unroll
  for (int d = 0; d < 9; ++d) {
    float4 v;
    v.x = acc[d][0] * 0.125f;
    v.y = acc[d][1] * 0.125f;
    v.z = acc[d][2] * 0.125f;
    v.w = acc[d][3] * 0.125f;
    *(float4*)(op + (size_t)d * HWsz) = v;
  }
}

extern "C" void kernel_launch(void* const* d_in, const int* in_sizes, int n_in,
                              void* d_out, int out_size, void* d_ws, size_t ws_size,
                              hipStream_t stream) {
  const float* x1 = (const float*)d_in[0];
  const float* x2 = (const float*)d_in[1];
  float* out = (float*)d_out;
  corr81_kernel<<<dim3(NBLOCKS), dim3(NTHREADS), 0, stream>>>(x1, x2, out);
}

// Round 14
// 205.904 us; speedup vs baseline: 4.0773x; 1.0242x over previous
//
#include <hip/hip_runtime.h>
#include <cstdint>

#define BB 8
#define CC 128
#define HH 96
#define WW 160
#define HWsz (HH * WW)                 // 15360
#define TH 8
#define TW 32
#define CSTEP 8
#define HROWS 10                       // halo rows for a dy-triple: TH + 2
#define SW 48                          // x2 row stride (40 used + pad), swizzle-closed
#define CIW (HROWS * SW)               // 480 words per channel slice
#define X2W (CSTEP * CIW)              // 3840 words = 15 KB per x2 buffer
#define X1W (CSTEP * TH * TW)          // 2048 words = 8 KB per x1 buffer
#define NWAVES 3
#define NTHREADS (NWAVES * 64)         // 192
#define NCHUNKS (CC / CSTEP)           // 16
#define NTILES (BB * (HH / TH) * (WW / TW))   // 480
#define NBLOCKS (NTILES * 3)           // 1440 blocks = (tile, dy-triple)
#define X1B (2 * X2W)                  // x1 region base: 7680 words
// LDS: 2*X2W + 2*X1W = 11776 words = 47104 B -> 3 blocks/CU co-residable

__device__ __forceinline__ void g2l_dword(const float* g, float* l) {
  __builtin_amdgcn_global_load_lds((const __attribute__((address_space(1))) void*)g,
                                   (__attribute__((address_space(3))) void*)l,
                                   4, 0, 0);
}

// R14 = R13 skeleton + 8-px channel-half compute (R1/R4-validated shape).
// Why: per-chunk DS-pipe busy (~290 b128 x 12-18 cyc ~ 4-5k cyc) is the
// largest term of the 8.2k-cyc chunk period and sits on the post-barrier
// critical path. 8-px shape: 24 b128 + 576 FMA per chunk-wave (vs 32+288) =
// 2.7x FMA per LDS read, with R4-MEASURED 2.2e6-conflict bank layout.
// It never ran unspilled at 576 threads (84-reg budget); R13 proved the
// 192-thread budget is 120 -> live ~110 fits. WRITE_SIZE=38880 is the
// spill tripwire; VGPR>128 aborts the branch.
// x1 is ALSO block-XOR-swizzled in LDS now: the 8-px x1 read (granule 2s)
// would be 4-way conflicted unswizzled; with block^(row&3) it is uniform
// 2/granule (free floor). Same involution discipline: source col permuted
// at stage time, read side applies the same XOR.
extern "C" __global__ void __launch_bounds__(NTHREADS, 2)
corr81_kernel(const float* __restrict__ x1, const float* __restrict__ x2,
              float* __restrict__ out)
{
  __shared__ __align__(16) float lds[2 * X2W + 2 * X1W];   // 47104 B

  const int tid  = threadIdx.x;
  const int wvu  = __builtin_amdgcn_readfirstlane(tid >> 6);  // wave 0..2
  const int lane = tid & 63;
  const int h    = lane >> 5;        // channel-half: ci = 4h..4h+3
  const int r    = (lane >> 2) & 7;  // tile row 0..7
  const int s    = lane & 3;         // 8-px col slot (cols 8s..8s+7)

  // XCD-bijective swizzle (validated): 1440 % 8 == 0.
  const int bid0 = blockIdx.x;
  const int bid  = (bid0 & 7) * (NBLOCKS / 8) + (bid0 >> 3);
  const int tile = bid / 3;
  const int g    = bid - 3 * tile;          // dy-triple index 0..2
  const int wt   = tile % (WW / TW);
  const int ht   = (tile / (WW / TW)) % (HH / TH);
  const int b    = tile / ((WW / TW) * (HH / TH));
  const int h0   = ht * TH;
  const int w0   = wt * TW;
  const int hb   = h0 + 3 * g - 4;          // halo row 0 source row (pre-clamp)

  // ---- scalar staging tables (R13 verbatim; compile-time indexed -> SGPRs).
  int grw[HROWS];
#pragma unroll
  for (int rr = 0; rr < HROWS; ++rr) {
    int v = hb + rr; v = v < 0 ? 0 : (v > HH - 1 ? HH - 1 : v);
    grw[rr] = v * WW;
  }
  int sc2[3], dc2[3], sx1[3], dx1[3];
#pragma unroll
  for (int c = 0; c < 3; ++c) {
    int ci = 3 * wvu + c; if (ci >= CSTEP) ci = 6;   // wl=2 remainder redirect
    sc2[c] = ci * HWsz;
    dc2[c] = ci * CIW;
    sx1[c] = ci * HWsz;
    dx1[c] = ci * (TH * TW);
  }
  int hqw[4];                               // x1 source row-pair bases
#pragma unroll
  for (int q = 0; q < 4; ++q) hqw[q] = (h0 + 2 * q) * WW + w0;

  // ---- per-lane staged columns for x2, one per swizzle class m (4 VGPRs).
  int gw[4];
#pragma unroll
  for (int mm = 0; mm < 4; ++mm) {
    const int cl = lane ^ (mm << 2);
    int v = w0 + cl - 4;
    gw[mm] = v < 0 ? 0 : (v > WW - 1 ? WW - 1 : v);
  }
  // x1 per-lane staging offsets, swizzled (2 VGPRs): slot q covers rows
  // 2q+hi (hi = lane>>5); phys col lo holds logical col lo^((row&3)<<2).
  {
  }
  const int hi1 = lane >> 5, lo1 = lane & 31;
  const int voffE = hi1 * WW + (lo1 ^ (hi1 << 2));          // q even: row&3 = hi
  const int voffO = hi1 * WW + (lo1 ^ ((2 | hi1) << 2));    // q odd : row&3 = 2+hi

  const float* x2b = x2 + (size_t)b * CC * HWsz;
  const float* x1b = x1 + (size_t)b * CC * HWsz;

  float acc[9][8];
#pragma unroll
  for (int d = 0; d < 9; ++d)
#pragma unroll
    for (int p = 0; p < 8; ++p) acc[d][p] = 0.f;

  // x2 LDS read bases (R4-measured layout): R = r + wl, m2 = R&3;
  // phys block of logical block L is L^m2; need L = 2s..2s+3.
  const int R  = r + wvu;                   // 0..9
  const int m2 = R & 3;
  int B4[4];
#pragma unroll
  for (int t = 0; t < 4; ++t)
    B4[t] = h * (4 * CIW) + R * SW + (((2 * s + t) ^ m2) << 2);
  // x1 LDS read bases: logical blocks 2s, 2s+1 of row r at phys ^(r&3).
  const int m1 = r & 3;
  const int A0 = h * 1024 + r * TW + (((2 * s + 0) ^ m1) << 2);
  const int A1 = h * 1024 + r * TW + (((2 * s + 1) ^ m1) << 2);

  // 42 loads per wave per chunk (30 x2 + 12 x1), counted uniformly.
#define STAGE(BUF, S2, S1)                                                   \
  {                                                                          \
    float* d2 = &lds[(BUF) * X2W];                                           \
    float* d1 = &lds[X1B + (BUF) * X1W];                                     \
    if (lane < SW) {                                                         \
      _Pragma("unroll")                                                      \
      for (int i = 0; i < 30; ++i) {                                         \
        const int c = i / 10, row = i % 10;                                  \
        g2l_dword((S2) + sc2[c] + grw[row] + gw[row & 3],                    \
                  d2 + dc2[c] + row * SW);                                   \
      }                                                                      \
    }                                                                        \
    _Pragma("unroll")                                                        \
    for (int i = 0; i < 12; ++i) {                                           \
      const int c = i / 4, q = i % 4;                                        \
      g2l_dword((S1) + sx1[c] + hqw[q] + ((q & 1) ? voffO : voffE),          \
                d1 + dx1[c] + q * 64);                                       \
    }                                                                        \
  }

#define COMPUTE(BUF)                                                         \
  {                                                                          \
    const float* xb = &lds[(BUF) * X2W];                                     \
    const float* ab = &lds[X1B + (BUF) * X1W];                               \
    _Pragma("unroll")                                                        \
    for (int q = 0; q < 4; ++q) {        /* ci = 4h + q */                   \
      const float4 a0 = *(const float4*)(ab + A0 + q * 256);                 \
      const float4 a1 = *(const float4*)(ab + A1 + q * 256);                 \
      const float av[8] = {a0.x, a0.y, a0.z, a0.w, a1.x, a1.y, a1.z, a1.w};  \
      float w16[16];                                                         \
      _Pragma("unroll")                                                      \
      for (int t = 0; t < 4; ++t) {                                          \
        const float4 f = *(const float4*)(xb + B4[t] + q * CIW);             \
        w16[4*t+0] = f.x; w16[4*t+1] = f.y;                                  \
        w16[4*t+2] = f.z; w16[4*t+3] = f.w;                                  \
      }                                                                      \
      _Pragma("unroll")                                                      \
      for (int d = 0; d < 9; ++d)                                            \
        _Pragma("unroll")                                                    \
        for (int p = 0; p < 8; ++p)                                          \
          acc[d][p] = fmaf(av[p], w16[d + p], acc[d][p]);                    \
    }                                                                        \
  }

  // ---- prologue: stage chunk 0 into buffer 0
  STAGE(0, x2b, x1b)

#pragma unroll 1
  for (int k = 0; k < NCHUNKS - 1; ++k) {
    // [A] issue stage(k+1)
    {
      const float* s2 = x2b + (size_t)(k + 1) * (CSTEP * HWsz);
      const float* s1 = x1b + (size_t)(k + 1) * (CSTEP * HWsz);
      STAGE((k + 1) & 1, s2, s1)
    }

    // [B] counted wait: drains stage(k)'s 42, keeps stage(k+1)'s 42 in flight
    __builtin_amdgcn_sched_barrier(0);
    asm volatile("s_waitcnt vmcnt(42)" ::: "memory");
    __builtin_amdgcn_sched_barrier(0);
    __builtin_amdgcn_s_barrier();             // 3-wave rendezvous
    __builtin_amdgcn_sched_barrier(0);

    // [D] compute chunk k: 16 x2 + 8 x1 ds_read_b128, 576 FMA per lane
    COMPUTE(k & 1)

    // [C2] WAR barrier
    __builtin_amdgcn_sched_barrier(0);
    __builtin_amdgcn_s_barrier();
    __builtin_amdgcn_sched_barrier(0);
  }

  // ---- peeled last chunk (k = 15, buf 1)
  asm volatile("s_waitcnt vmcnt(0)" ::: "memory");
  __builtin_amdgcn_sched_barrier(0);
  __builtin_amdgcn_s_barrier();
  __builtin_amdgcn_sched_barrier(0);
  COMPUTE((NCHUNKS - 1) & 1)

  // ---- epilogue (R4-validated): combine channel-halves across lane^32, /8.
  // dy = 3g + wl; lane writes cols w0 + 8s + 4h .. +3.
  const int dy = 3 * g + wvu;
  float* op = out + (((size_t)b * 81 + (size_t)dy * 9) * HH + (h0 + r)) * WW
                  + (w0 + 8 * s + 4 * h);
#pragma unroll
  for (int d = 0; d < 9; ++d) {
    const float own0 = h ? acc[d][4] : acc[d][0];
    const float own1 = h ? acc[d][5] : acc[d][1];
    const float own2 = h ? acc[d][6] : acc[d][2];
    const float own3 = h ? acc[d][7] : acc[d][3];
    const float snd0 = h ? acc[d][0] : acc[d][4];
    const float snd1 = h ? acc[d][1] : acc[d][5];
    const float snd2 = h ? acc[d][2] : acc[d][6];
    const float snd3 = h ? acc[d][3] : acc[d][7];
    float4 v;
    v.x = (own0 + __shfl_xor(snd0, 32)) * 0.125f;
    v.y = (own1 + __shfl_xor(snd1, 32)) * 0.125f;
    v.z = (own2 + __shfl_xor(snd2, 32)) * 0.125f;
    v.w = (own3 + __shfl_xor(snd3, 32)) * 0.125f;
    *(float4*)(op + (size_t)d * HWsz) = v;
  }
}

extern "C" void kernel_launch(void* const* d_in, const int* in_sizes, int n_in,
                              void* d_out, int out_size, void* d_ws, size_t ws_size,
                              hipStream_t stream) {
  const float* x1 = (const float*)d_in[0];
  const float* x2 = (const float*)d_in[1];
  float* out = (float*)d_out;
  corr81_kernel<<<dim3(NBLOCKS), dim3(NTHREADS), 0, stream>>>(x1, x2, out);
}